// Round 1
// baseline (6476.662 us; speedup 1.0000x reference)
//
#include <hip/hip_runtime.h>

// SNN forward, xs-path only (ys/requant path is dead code w.r.t. the output).
// Layout everywhere: (N, C, H, W, T) with T=40 innermost, fp32.

constexpr int NT = 40;

// ---------------- conv scheme A: block=(COUT threads), one thread per out-channel,
// grid = (HO*WO, NT/TCH, N). Input loads are wave-uniform (broadcast). ----------------
template<int CIN, int COUT, int H, int W, int PAD, int TCH>
__global__ __launch_bounds__(COUT) void conv_a(
    const float* __restrict__ in, const float* __restrict__ wt,
    const float* __restrict__ bias, float* __restrict__ out)
{
    constexpr int HO = PAD ? H : (H - 2);
    constexpr int WO = PAD ? W : (W - 2);
    constexpr int NQ = TCH / 4;
    const int co = threadIdx.x;
    const int sp = blockIdx.x;
    const int ho = sp / WO, wo = sp % WO;
    const int t0 = blockIdx.y * TCH;
    const int n  = blockIdx.z;

    float4 acc[NQ];
    const float bv = bias[co];
#pragma unroll
    for (int q = 0; q < NQ; q++) { acc[q].x = bv; acc[q].y = bv; acc[q].z = bv; acc[q].w = bv; }

    const float* wrow = wt + (size_t)co * (CIN * 9);
    for (int ci = 0; ci < CIN; ci++) {
        const float* inc = in + ((size_t)(n * CIN + ci) * (H * W)) * NT;
#pragma unroll
        for (int kh = 0; kh < 3; kh++) {
            const int hi = ho + kh - PAD;
            if (hi < 0 || hi >= H) continue;
#pragma unroll
            for (int kw = 0; kw < 3; kw++) {
                const int wi = wo + kw - PAD;
                if (wi < 0 || wi >= W) continue;
                const float wv = wrow[ci * 9 + kh * 3 + kw];
                const float4* ip = reinterpret_cast<const float4*>(
                    inc + ((size_t)hi * W + wi) * NT + t0);
#pragma unroll
                for (int q = 0; q < NQ; q++) {
                    float4 xv = ip[q];
                    acc[q].x += xv.x * wv;
                    acc[q].y += xv.y * wv;
                    acc[q].z += xv.z * wv;
                    acc[q].w += xv.w * wv;
                }
            }
        }
    }
    float4* op = reinterpret_cast<float4*>(
        out + ((((size_t)n * COUT + co) * HO + ho) * WO + wo) * NT + t0);
#pragma unroll
    for (int q = 0; q < NQ; q++) op[q] = acc[q];
}

// ---------------- conv scheme B (conv7, 4x4 -> 2x2, pad 0): block = 40t x 16co,
// grid = (COUT/16, HO*WO, N). t-lanes coalesce on input. ----------------
template<int CIN, int COUT, int H>
__global__ __launch_bounds__(640) void conv_b(
    const float* __restrict__ in, const float* __restrict__ wt,
    const float* __restrict__ bias, float* __restrict__ out)
{
    constexpr int W = H;
    constexpr int HO = H - 2, WO = W - 2;
    const int t  = threadIdx.x % NT;
    const int cs = threadIdx.x / NT;         // 0..15
    const int co = blockIdx.x * 16 + cs;
    const int sp = blockIdx.y;
    const int ho = sp / WO, wo = sp % WO;
    const int n  = blockIdx.z;

    float acc = bias[co];
    const float* wrow = wt + (size_t)co * (CIN * 9);
    for (int ci = 0; ci < CIN; ci++) {
        const float* inc = in + ((size_t)(n * CIN + ci) * (H * W)) * NT + t;
#pragma unroll
        for (int kh = 0; kh < 3; kh++) {
#pragma unroll
            for (int kw = 0; kw < 3; kw++) {
                acc += inc[((size_t)(ho + kh) * W + (wo + kw)) * NT]
                     * wrow[ci * 9 + kh * 3 + kw];
            }
        }
    }
    out[((((size_t)n * COUT + co) * HO + ho) * WO + wo) * NT + t] = acc;
}

// ---------------- integrate-and-fire scan over T, soft reset, in-place ----------------
__global__ void if_kernel(float* __restrict__ buf, const float* __restrict__ thr,
                          int C, int HW, int total)
{
    int idx = blockIdx.x * blockDim.x + threadIdx.x;
    if (idx >= total) return;
    const float th = thr[(idx / HW) % C];
    float4* p = reinterpret_cast<float4*>(buf + (size_t)idx * NT);
    float v = 0.f;
#pragma unroll
    for (int q = 0; q < NT / 4; q++) {
        float4 x = p[q];
        float s;
        v += x.x; s = (v >= th) ? 1.f : 0.f; v -= s * th; x.x = s;
        v += x.y; s = (v >= th) ? 1.f : 0.f; v -= s * th; x.y = s;
        v += x.z; s = (v >= th) ? 1.f : 0.f; v -= s * th; x.z = s;
        v += x.w; s = (v >= th) ? 1.f : 0.f; v -= s * th; x.w = s;
        p[q] = x;
    }
}

// ---------------- 2x2 avg-pool (per t) fused with IF scan ----------------
__global__ void pool_if_kernel(const float* __restrict__ in, float* __restrict__ out,
                               const float* __restrict__ thr,
                               int C, int HO, int WO, int total)
{
    int idx = blockIdx.x * blockDim.x + threadIdx.x;
    if (idx >= total) return;
    const int wo = idx % WO;
    const int ho = (idx / WO) % HO;
    const int c  = (idx / (WO * HO)) % C;
    const int n  = idx / (WO * HO * C);
    const int H = HO * 2, W = WO * 2;
    const float th = thr[c];
    const float* base = in + (((size_t)(n * C + c) * H + 2 * ho) * W + 2 * wo) * NT;
    const float4* p00 = reinterpret_cast<const float4*>(base);
    const float4* p01 = reinterpret_cast<const float4*>(base + NT);
    const float4* p10 = reinterpret_cast<const float4*>(base + (size_t)W * NT);
    const float4* p11 = reinterpret_cast<const float4*>(base + (size_t)W * NT + NT);
    float4* q = reinterpret_cast<float4*>(
        out + (((size_t)(n * C + c) * HO + ho) * WO + wo) * NT);
    float v = 0.f;
#pragma unroll
    for (int k = 0; k < NT / 4; k++) {
        float4 a = p00[k], b = p01[k], cc = p10[k], d = p11[k];
        float4 o;
        float m, s;
        m = (a.x + b.x + cc.x + d.x) * 0.25f; v += m; s = (v >= th) ? 1.f : 0.f; v -= s * th; o.x = s;
        m = (a.y + b.y + cc.y + d.y) * 0.25f; v += m; s = (v >= th) ? 1.f : 0.f; v -= s * th; o.y = s;
        m = (a.z + b.z + cc.z + d.z) * 0.25f; v += m; s = (v >= th) ? 1.f : 0.f; v -= s * th; o.z = s;
        m = (a.w + b.w + cc.w + d.w) * 0.25f; v += m; s = (v >= th) ? 1.f : 0.f; v -= s * th; o.w = s;
        q[k] = o;
    }
}

// ---------------- classifier: out[n,o] = bc[o] + (1/T) * sum_c count[n,c]*wc[o,c] ----------------
__global__ __launch_bounds__(1024) void classifier_kernel(
    const float* __restrict__ s, const float* __restrict__ wc,
    const float* __restrict__ bc, float* __restrict__ out)
{
    __shared__ float cnt[2][1024];
    const int c = threadIdx.x;
    for (int n = 0; n < 2; n++) {
        const float4* p = reinterpret_cast<const float4*>(s + ((size_t)n * 1024 + c) * NT);
        float sum = 0.f;
#pragma unroll
        for (int k = 0; k < NT / 4; k++) { float4 x = p[k]; sum += x.x + x.y + x.z + x.w; }
        cnt[n][c] = sum;
    }
    __syncthreads();
    if (threadIdx.x < 20) {
        const int n = threadIdx.x / 10, o = threadIdx.x % 10;
        float a = 0.f;
        for (int k = 0; k < 1024; k++) a += cnt[n][k] * wc[o * 1024 + k];
        out[n * 10 + o] = a * (1.f / 40.f) + bc[o];
    }
}

extern "C" void kernel_launch(void* const* d_in, const int* in_sizes, int n_in,
                              void* d_out, int out_size, void* d_ws, size_t ws_size,
                              hipStream_t stream)
{
    const float* x   = (const float*)d_in[0];
    const float* w1  = (const float*)d_in[1];  const float* b1 = (const float*)d_in[2];
    const float* w2  = (const float*)d_in[3];  const float* b2 = (const float*)d_in[4];
    const float* w3  = (const float*)d_in[5];  const float* b3 = (const float*)d_in[6];
    const float* w4  = (const float*)d_in[7];  const float* b4 = (const float*)d_in[8];
    const float* w5  = (const float*)d_in[9];  const float* b5 = (const float*)d_in[10];
    const float* w6  = (const float*)d_in[11]; const float* b6 = (const float*)d_in[12];
    const float* w7  = (const float*)d_in[13]; const float* b7 = (const float*)d_in[14];
    const float* wc  = (const float*)d_in[15]; const float* bc = (const float*)d_in[16];
    const float* thr1 = (const float*)d_in[17];
    const float* thr2 = (const float*)d_in[18];
    const float* p1   = (const float*)d_in[19];
    const float* thr3 = (const float*)d_in[20];
    const float* thr4 = (const float*)d_in[21];
    const float* p2   = (const float*)d_in[22];
    const float* thr5 = (const float*)d_in[23];
    const float* thr6 = (const float*)d_in[24];
    const float* p3   = (const float*)d_in[25];
    const float* thr7 = (const float*)d_in[26];
    const float* p4   = (const float*)d_in[27];

    float* A = (float*)d_ws;                                         // 44 MB region
    float* B = (float*)((char*)d_ws + (size_t)44 * 1024 * 1024);     // 44 MB region
    float* O = (float*)d_out;

    // L1: conv1 3->128 @32x32 pad1, x -> A; IF(thr1)
    conv_a<3, 128, 32, 32, 1, 40><<<dim3(1024, 1, 2), 128, 0, stream>>>(x, w1, b1, A);
    if_kernel<<<1024, 256, 0, stream>>>(A, thr1, 128, 1024, 262144);
    // L2: conv2 128->128 @32x32, A -> B; IF(thr2)
    conv_a<128, 128, 32, 32, 1, 40><<<dim3(1024, 1, 2), 128, 0, stream>>>(A, w2, b2, B);
    if_kernel<<<1024, 256, 0, stream>>>(B, thr2, 128, 1024, 262144);
    // P1: pool+IF(p1), B -> A (2,128,16,16,T)
    pool_if_kernel<<<256, 256, 0, stream>>>(B, A, p1, 128, 16, 16, 65536);
    // L3: conv3 128->256 @16x16, A -> B; IF(thr3)
    conv_a<128, 256, 16, 16, 1, 40><<<dim3(256, 1, 2), 256, 0, stream>>>(A, w3, b3, B);
    if_kernel<<<512, 256, 0, stream>>>(B, thr3, 256, 256, 131072);
    // L4: conv4 256->256 @16x16, B -> A; IF(thr4)
    conv_a<256, 256, 16, 16, 1, 40><<<dim3(256, 1, 2), 256, 0, stream>>>(B, w4, b4, A);
    if_kernel<<<512, 256, 0, stream>>>(A, thr4, 256, 256, 131072);
    // P2: pool+IF(p2), A -> B (2,256,8,8,T)
    pool_if_kernel<<<128, 256, 0, stream>>>(A, B, p2, 256, 8, 8, 32768);
    // L5: conv5 256->512 @8x8, B -> A; IF(thr5)
    conv_a<256, 512, 8, 8, 1, 20><<<dim3(64, 2, 2), 512, 0, stream>>>(B, w5, b5, A);
    if_kernel<<<256, 256, 0, stream>>>(A, thr5, 512, 64, 65536);
    // L6: conv6 512->512 @8x8, A -> B; IF(thr6)
    conv_a<512, 512, 8, 8, 1, 20><<<dim3(64, 2, 2), 512, 0, stream>>>(A, w6, b6, B);
    if_kernel<<<256, 256, 0, stream>>>(B, thr6, 512, 64, 65536);
    // P3: pool+IF(p3), B -> A (2,512,4,4,T)
    pool_if_kernel<<<64, 256, 0, stream>>>(B, A, p3, 512, 4, 4, 16384);
    // L7: conv7 512->1024 @4x4 pad0 -> 2x2, A -> B; IF(thr7)
    conv_b<512, 1024, 4><<<dim3(64, 4, 2), 640, 0, stream>>>(A, w7, b7, B);
    if_kernel<<<32, 256, 0, stream>>>(B, thr7, 1024, 4, 8192);
    // P4: pool+IF(p4), B -> A (2,1024,1,1,T)
    pool_if_kernel<<<8, 256, 0, stream>>>(B, A, p4, 1024, 1, 1, 2048);
    // classifier
    classifier_kernel<<<1, 1024, 0, stream>>>(A, wc, bc, O);
}

// Round 2
// 2293.696 us; speedup vs baseline: 2.8237x; 2.8237x over previous
//
#include <hip/hip_runtime.h>

// SNN forward, xs-path only. Layout (N, C, H, W, T), T=40 innermost, fp32.
// Scheme C convs: pre-transposed weights [ci*9][co], LDS-staged input patch +
// weight chunk, 4co x 4t outer-product per thread.

constexpr int NT = 40;

__device__ __forceinline__ void fma4(float4& a, const float4& x, float w) {
    a.x = fmaf(x.x, w, a.x); a.y = fmaf(x.y, w, a.y);
    a.z = fmaf(x.z, w, a.z); a.w = fmaf(x.w, w, a.w);
}

// ---------------- weight transpose: w[CO][R] -> wt[R][CO], R = CIN*9 ----------------
__global__ __launch_bounds__(256) void transpose_w(
    const float* __restrict__ w, float* __restrict__ wt, int CO, int R)
{
    __shared__ float tile[32][33];
    const int r0 = blockIdx.x * 32, c0 = blockIdx.y * 32;
    const int tx = threadIdx.x % 32, ty = threadIdx.x / 32;   // 32 x 8
#pragma unroll
    for (int k = 0; k < 4; k++) {
        const int co = c0 + ty + k * 8, r = r0 + tx;
        if (co < CO && r < R) tile[ty + k * 8][tx] = w[(size_t)co * R + r];
    }
    __syncthreads();
#pragma unroll
    for (int k = 0; k < 4; k++) {
        const int r = r0 + ty + k * 8, co = c0 + tx;
        if (r < R && co < CO) wt[(size_t)r * CO + co] = tile[tx][ty + k * 8];
    }
}

// ---------------- conv scheme C ----------------
// block = 320 threads = 10 t-groups (4 t each) x 32 co-groups (4 co each).
// grid = (HO*WO, COUT/CO_BLK, N*NSPLIT). NSPLIT splits ci; split s writes
// partial sums to out + s*slab (bias added by split 0 only).
template<int CIN, int COUT, int H, int W, int PAD, int CO_BLK, int CB, int NSPLIT>
__global__ __launch_bounds__(320) void conv_c(
    const float* __restrict__ in, const float* __restrict__ wt,
    const float* __restrict__ bias, float* __restrict__ out)
{
    constexpr int HO = PAD ? H : (H - 2);
    constexpr int WO = PAD ? W : (W - 2);
    constexpr int ROWS = CB * 9;
    constexpr int CIS = CIN / NSPLIT;
    constexpr int CHUNKS = CIS / CB;
    constexpr int XU = ROWS * (NT / 4);
    constexpr int WU = ROWS * (CO_BLK / 4);

    __shared__ float xs[ROWS * NT];
    __shared__ float wl[ROWS * CO_BLK];

    const int sp = blockIdx.x;
    const int ho = sp / WO, wo = sp % WO;
    const int co0 = blockIdx.y * CO_BLK;
    const int n = blockIdx.z / NSPLIT, split = blockIdx.z % NSPLIT;
    const int tid = threadIdx.x;
    const int tt = tid >> 5;        // 0..9  (t = tt*4 .. tt*4+3)
    const int cc = tid & 31;        // 0..31 (co = co0 + cc*4 + j)

    float4 acc[4];
#pragma unroll
    for (int j = 0; j < 4; j++) {
        const float bv = (split == 0) ? bias[co0 + cc * 4 + j] : 0.f;
        acc[j] = make_float4(bv, bv, bv, bv);
    }

    for (int ch = 0; ch < CHUNKS; ++ch) {
        const int ci0 = split * CIS + ch * CB;
        // stage x patch: rows (ci_local, k) x 40 t, zero-padded at edges
        for (int u = tid; u < XU; u += 320) {
            const int r = u / (NT / 4), q = u % (NT / 4);
            const int cil = r / 9, k = r % 9;
            const int hi = ho + k / 3 - PAD, wi = wo + k % 3 - PAD;
            float4 v = make_float4(0.f, 0.f, 0.f, 0.f);
            if (PAD == 0 || ((unsigned)hi < (unsigned)H && (unsigned)wi < (unsigned)W))
                v = *reinterpret_cast<const float4*>(
                    in + (((size_t)(n * CIN + ci0 + cil) * H + hi) * W + wi) * NT + q * 4);
            *reinterpret_cast<float4*>(&xs[r * NT + q * 4]) = v;
        }
        // stage weight chunk (coalesced rows of pre-transposed WT)
        const float* wsrc = wt + (size_t)(ci0 * 9) * COUT + co0;
        for (int u = tid; u < WU; u += 320) {
            const int r = u / (CO_BLK / 4), j = u % (CO_BLK / 4);
            *reinterpret_cast<float4*>(&wl[r * CO_BLK + j * 4]) =
                *reinterpret_cast<const float4*>(wsrc + (size_t)r * COUT + j * 4);
        }
        __syncthreads();
#pragma unroll 9
        for (int r = 0; r < ROWS; ++r) {
            const float4 xv = *reinterpret_cast<const float4*>(&xs[r * NT + tt * 4]);
            const float4 wv = *reinterpret_cast<const float4*>(&wl[r * CO_BLK + cc * 4]);
            fma4(acc[0], xv, wv.x);
            fma4(acc[1], xv, wv.y);
            fma4(acc[2], xv, wv.z);
            fma4(acc[3], xv, wv.w);
        }
        __syncthreads();
    }

    const size_t slab = (size_t)2 * COUT * HO * WO * NT;
    float* op = out + (size_t)split * slab;
#pragma unroll
    for (int j = 0; j < 4; j++) {
        const int co = co0 + cc * 4 + j;
        *reinterpret_cast<float4*>(
            op + ((((size_t)n * COUT + co) * HO + ho) * WO + wo) * NT + tt * 4) = acc[j];
    }
}

// ---------------- integrate-and-fire scan over T, soft reset, in-place ----------------
__global__ void if_kernel(float* __restrict__ buf, const float* __restrict__ thr,
                          int C, int HW, int total)
{
    int idx = blockIdx.x * blockDim.x + threadIdx.x;
    if (idx >= total) return;
    const float th = thr[(idx / HW) % C];
    float4* p = reinterpret_cast<float4*>(buf + (size_t)idx * NT);
    float v = 0.f;
#pragma unroll
    for (int q = 0; q < NT / 4; q++) {
        float4 x = p[q];
        float s;
        v += x.x; s = (v >= th) ? 1.f : 0.f; v -= s * th; x.x = s;
        v += x.y; s = (v >= th) ? 1.f : 0.f; v -= s * th; x.y = s;
        v += x.z; s = (v >= th) ? 1.f : 0.f; v -= s * th; x.z = s;
        v += x.w; s = (v >= th) ? 1.f : 0.f; v -= s * th; x.w = s;
        p[q] = x;
    }
}

// ---------------- 4-way partial-sum reduce + IF (layer 7) ----------------
__global__ void reduce_if_kernel(const float* __restrict__ part, float* __restrict__ out,
                                 const float* __restrict__ thr, int C, int HW, int total,
                                 size_t slab)
{
    int idx = blockIdx.x * blockDim.x + threadIdx.x;
    if (idx >= total) return;
    const float th = thr[(idx / HW) % C];
    float v = 0.f;
    float4* op = reinterpret_cast<float4*>(out + (size_t)idx * NT);
#pragma unroll
    for (int q = 0; q < NT / 4; q++) {
        float4 x0 = *reinterpret_cast<const float4*>(part + (size_t)idx * NT + q * 4);
        float4 x1 = *reinterpret_cast<const float4*>(part + slab + (size_t)idx * NT + q * 4);
        float4 x2 = *reinterpret_cast<const float4*>(part + 2 * slab + (size_t)idx * NT + q * 4);
        float4 x3 = *reinterpret_cast<const float4*>(part + 3 * slab + (size_t)idx * NT + q * 4);
        x0.x = ((x0.x + x1.x) + x2.x) + x3.x;
        x0.y = ((x0.y + x1.y) + x2.y) + x3.y;
        x0.z = ((x0.z + x1.z) + x2.z) + x3.z;
        x0.w = ((x0.w + x1.w) + x2.w) + x3.w;
        float s; float4 o;
        v += x0.x; s = (v >= th) ? 1.f : 0.f; v -= s * th; o.x = s;
        v += x0.y; s = (v >= th) ? 1.f : 0.f; v -= s * th; o.y = s;
        v += x0.z; s = (v >= th) ? 1.f : 0.f; v -= s * th; o.z = s;
        v += x0.w; s = (v >= th) ? 1.f : 0.f; v -= s * th; o.w = s;
        op[q] = o;
    }
}

// ---------------- 2x2 avg-pool (per t) fused with IF scan ----------------
__global__ void pool_if_kernel(const float* __restrict__ in, float* __restrict__ out,
                               const float* __restrict__ thr,
                               int C, int HO, int WO, int total)
{
    int idx = blockIdx.x * blockDim.x + threadIdx.x;
    if (idx >= total) return;
    const int wo = idx % WO;
    const int ho = (idx / WO) % HO;
    const int c  = (idx / (WO * HO)) % C;
    const int n  = idx / (WO * HO * C);
    const int H = HO * 2, W = WO * 2;
    const float th = thr[c];
    const float* base = in + (((size_t)(n * C + c) * H + 2 * ho) * W + 2 * wo) * NT;
    const float4* p00 = reinterpret_cast<const float4*>(base);
    const float4* p01 = reinterpret_cast<const float4*>(base + NT);
    const float4* p10 = reinterpret_cast<const float4*>(base + (size_t)W * NT);
    const float4* p11 = reinterpret_cast<const float4*>(base + (size_t)W * NT + NT);
    float4* q = reinterpret_cast<float4*>(
        out + (((size_t)(n * C + c) * HO + ho) * WO + wo) * NT);
    float v = 0.f;
#pragma unroll
    for (int k = 0; k < NT / 4; k++) {
        float4 a = p00[k], b = p01[k], cc = p10[k], d = p11[k];
        float4 o;
        float m, s;
        m = (a.x + b.x + cc.x + d.x) * 0.25f; v += m; s = (v >= th) ? 1.f : 0.f; v -= s * th; o.x = s;
        m = (a.y + b.y + cc.y + d.y) * 0.25f; v += m; s = (v >= th) ? 1.f : 0.f; v -= s * th; o.y = s;
        m = (a.z + b.z + cc.z + d.z) * 0.25f; v += m; s = (v >= th) ? 1.f : 0.f; v -= s * th; o.z = s;
        m = (a.w + b.w + cc.w + d.w) * 0.25f; v += m; s = (v >= th) ? 1.f : 0.f; v -= s * th; o.w = s;
        q[k] = o;
    }
}

// ---------------- classifier ----------------
__global__ __launch_bounds__(1024) void classifier_kernel(
    const float* __restrict__ s, const float* __restrict__ wc,
    const float* __restrict__ bc, float* __restrict__ out)
{
    __shared__ float cnt[2][1024];
    const int c = threadIdx.x;
    for (int n = 0; n < 2; n++) {
        const float4* p = reinterpret_cast<const float4*>(s + ((size_t)n * 1024 + c) * NT);
        float sum = 0.f;
#pragma unroll
        for (int k = 0; k < NT / 4; k++) { float4 x = p[k]; sum += x.x + x.y + x.z + x.w; }
        cnt[n][c] = sum;
    }
    __syncthreads();
    if (threadIdx.x < 20) {
        const int n = threadIdx.x / 10, o = threadIdx.x % 10;
        float a = 0.f;
        for (int k = 0; k < 1024; k++) a += cnt[n][k] * wc[o * 1024 + k];
        out[n * 10 + o] = a * (1.f / 40.f) + bc[o];
    }
}

extern "C" void kernel_launch(void* const* d_in, const int* in_sizes, int n_in,
                              void* d_out, int out_size, void* d_ws, size_t ws_size,
                              hipStream_t stream)
{
    const float* x   = (const float*)d_in[0];
    const float* w1  = (const float*)d_in[1];  const float* b1 = (const float*)d_in[2];
    const float* w2  = (const float*)d_in[3];  const float* b2 = (const float*)d_in[4];
    const float* w3  = (const float*)d_in[5];  const float* b3 = (const float*)d_in[6];
    const float* w4  = (const float*)d_in[7];  const float* b4 = (const float*)d_in[8];
    const float* w5  = (const float*)d_in[9];  const float* b5 = (const float*)d_in[10];
    const float* w6  = (const float*)d_in[11]; const float* b6 = (const float*)d_in[12];
    const float* w7  = (const float*)d_in[13]; const float* b7 = (const float*)d_in[14];
    const float* wc  = (const float*)d_in[15]; const float* bc = (const float*)d_in[16];
    const float* thr1 = (const float*)d_in[17];
    const float* thr2 = (const float*)d_in[18];
    const float* p1   = (const float*)d_in[19];
    const float* thr3 = (const float*)d_in[20];
    const float* thr4 = (const float*)d_in[21];
    const float* p2   = (const float*)d_in[22];
    const float* thr5 = (const float*)d_in[23];
    const float* thr6 = (const float*)d_in[24];
    const float* p3   = (const float*)d_in[25];
    const float* thr7 = (const float*)d_in[26];
    const float* p4   = (const float*)d_in[27];

    float* A  = (float*)d_ws;                                        // 44 MB
    float* B  = (float*)((char*)d_ws + ((size_t)44 << 20));          // 44 MB
    float* WT = (float*)((char*)d_ws + ((size_t)88 << 20));          // ~37.2 MB
    float* wt1 = WT;             // 27 x 128
    float* wt2 = WT + 3456;      // 1152 x 128
    float* wt3 = WT + 150912;    // 1152 x 256
    float* wt4 = WT + 445824;    // 2304 x 256
    float* wt5 = WT + 1035648;   // 2304 x 512
    float* wt6 = WT + 2215296;   // 4608 x 512
    float* wt7 = WT + 4574592;   // 4608 x 1024
    float* S7 = A + 1048576;     // conv7 spikes (2,1024,2,2,40), A live region is 2.62MB
    float* P4 = B + 2097152;     // pool4 spikes (2,1024,1,1,40), B partials live at 0..5.3MB
    float* O  = (float*)d_out;

    // weight transposes: w[CO][CIN*9] -> wt[CIN*9][CO]
    transpose_w<<<dim3(1, 4),   256, 0, stream>>>(w1, wt1, 128, 27);
    transpose_w<<<dim3(36, 4),  256, 0, stream>>>(w2, wt2, 128, 1152);
    transpose_w<<<dim3(36, 8),  256, 0, stream>>>(w3, wt3, 256, 1152);
    transpose_w<<<dim3(72, 8),  256, 0, stream>>>(w4, wt4, 256, 2304);
    transpose_w<<<dim3(72, 16), 256, 0, stream>>>(w5, wt5, 512, 2304);
    transpose_w<<<dim3(144, 16),256, 0, stream>>>(w6, wt6, 512, 4608);
    transpose_w<<<dim3(144, 32),256, 0, stream>>>(w7, wt7, 1024, 4608);

    // L1: conv1 3->128 @32x32 pad1, x -> A; IF(thr1)
    conv_c<3, 128, 32, 32, 1, 128, 3, 1><<<dim3(1024, 1, 2), 320, 0, stream>>>(x, wt1, b1, A);
    if_kernel<<<1024, 256, 0, stream>>>(A, thr1, 128, 1024, 262144);
    // L2: conv2 128->128, A -> B; IF(thr2)
    conv_c<128, 128, 32, 32, 1, 128, 8, 1><<<dim3(1024, 1, 2), 320, 0, stream>>>(A, wt2, b2, B);
    if_kernel<<<1024, 256, 0, stream>>>(B, thr2, 128, 1024, 262144);
    // P1: pool+IF(p1), B -> A (2,128,16,16,T)
    pool_if_kernel<<<256, 256, 0, stream>>>(B, A, p1, 128, 16, 16, 65536);
    // L3: conv3 128->256 @16x16, A -> B; IF(thr3)
    conv_c<128, 256, 16, 16, 1, 128, 8, 1><<<dim3(256, 2, 2), 320, 0, stream>>>(A, wt3, b3, B);
    if_kernel<<<512, 256, 0, stream>>>(B, thr3, 256, 256, 131072);
    // L4: conv4 256->256, B -> A; IF(thr4)
    conv_c<256, 256, 16, 16, 1, 128, 8, 1><<<dim3(256, 2, 2), 320, 0, stream>>>(B, wt4, b4, A);
    if_kernel<<<512, 256, 0, stream>>>(A, thr4, 256, 256, 131072);
    // P2: pool+IF(p2), A -> B (2,256,8,8,T)
    pool_if_kernel<<<128, 256, 0, stream>>>(A, B, p2, 256, 8, 8, 32768);
    // L5: conv5 256->512 @8x8, B -> A; IF(thr5)
    conv_c<256, 512, 8, 8, 1, 128, 8, 1><<<dim3(64, 4, 2), 320, 0, stream>>>(B, wt5, b5, A);
    if_kernel<<<256, 256, 0, stream>>>(A, thr5, 512, 64, 65536);
    // L6: conv6 512->512, A -> B; IF(thr6)
    conv_c<512, 512, 8, 8, 1, 128, 8, 1><<<dim3(64, 4, 2), 320, 0, stream>>>(A, wt6, b6, B);
    if_kernel<<<256, 256, 0, stream>>>(B, thr6, 512, 64, 65536);
    // P3: pool+IF(p3), B -> A (2,512,4,4,T)
    pool_if_kernel<<<64, 256, 0, stream>>>(B, A, p3, 512, 4, 4, 16384);
    // L7: conv7 512->1024 @4x4 pad0, ci-split x4: A -> B partials; reduce+IF -> S7
    conv_c<512, 1024, 4, 4, 0, 128, 8, 4><<<dim3(4, 8, 8), 320, 0, stream>>>(A, wt7, b7, B);
    reduce_if_kernel<<<32, 256, 0, stream>>>(B, S7, thr7, 1024, 4, 8192, 327680);
    // P4: pool+IF(p4), S7 -> P4 (2,1024,1,1,T)
    pool_if_kernel<<<8, 256, 0, stream>>>(S7, P4, p4, 1024, 1, 1, 2048);
    // classifier
    classifier_kernel<<<1, 1024, 0, stream>>>(P4, wc, bc, O);
}

// Round 3
// 562.301 us; speedup vs baseline: 11.5181x; 4.0791x over previous
//
#include <hip/hip_runtime.h>

// SNN forward, xs-path only. Intermediates channel-innermost: (N,H,W,T,C), T=40.
// Convs 2-7: MFMA 16x16x32 bf16 with EXACT 3-way bf16 weight split (hi/mid/lo
// by mantissa truncation; spikes are {0,1} = exact bf16, so products are exact).

constexpr int NT = 40;

typedef __attribute__((ext_vector_type(8))) short s16x8;
typedef __attribute__((ext_vector_type(4))) float f32x4;

__device__ __forceinline__ float bf2f(unsigned short u) {
    return __uint_as_float(((unsigned)u) << 16);
}

// ---------------- weight transpose for conv1: w[CO][R] -> wt[R][CO] ----------------
__global__ __launch_bounds__(256) void transpose_w(
    const float* __restrict__ w, float* __restrict__ wt, int CO, int R)
{
    __shared__ float tile[32][33];
    const int r0 = blockIdx.x * 32, c0 = blockIdx.y * 32;
    const int tx = threadIdx.x % 32, ty = threadIdx.x / 32;
#pragma unroll
    for (int k = 0; k < 4; k++) {
        const int co = c0 + ty + k * 8, r = r0 + tx;
        if (co < CO && r < R) tile[ty + k * 8][tx] = w[(size_t)co * R + r];
    }
    __syncthreads();
#pragma unroll
    for (int k = 0; k < 4; k++) {
        const int r = r0 + ty + k * 8, co = c0 + tx;
        if (r < R && co < CO) wt[(size_t)r * CO + co] = tile[tx][ty + k * 8];
    }
}

// ---------------- conv1: 3->128 @32x32 pad1, fp32 VALU, out channel-innermost ----------------
__global__ __launch_bounds__(320) void conv1_c(
    const float* __restrict__ in, const float* __restrict__ wt,
    const float* __restrict__ bias, float* __restrict__ out)
{
    __shared__ float xs_[27 * NT];
    __shared__ float wl[27 * 128];
    const int sp = blockIdx.x;
    const int ho = sp >> 5, wo = sp & 31;
    const int n = blockIdx.z;
    const int tid = threadIdx.x;
    const int tt = tid >> 5;        // 0..9
    const int cc = tid & 31;        // 0..31

    float4 acc[4];
#pragma unroll
    for (int j = 0; j < 4; j++) {
        const float bv = bias[cc * 4 + j];
        acc[j] = make_float4(bv, bv, bv, bv);
    }
    for (int u = tid; u < 270; u += 320) {
        const int r = u / 10, q = u % 10;
        const int cil = r / 9, k = r % 9;
        const int hi = ho + k / 3 - 1, wi = wo + k % 3 - 1;
        float4 v = make_float4(0.f, 0.f, 0.f, 0.f);
        if ((unsigned)hi < 32u && (unsigned)wi < 32u)
            v = *reinterpret_cast<const float4*>(
                in + ((size_t)((n * 3 + cil) * 1024 + hi * 32 + wi)) * NT + q * 4);
        *reinterpret_cast<float4*>(&xs_[r * NT + q * 4]) = v;
    }
    for (int u = tid; u < 864; u += 320) {
        const int r = u >> 5, j = u & 31;
        *reinterpret_cast<float4*>(&wl[r * 128 + j * 4]) =
            *reinterpret_cast<const float4*>(wt + r * 128 + j * 4);
    }
    __syncthreads();
#pragma unroll
    for (int r = 0; r < 27; ++r) {
        const float4 xv = *reinterpret_cast<const float4*>(&xs_[r * NT + tt * 4]);
        const float4 wv = *reinterpret_cast<const float4*>(&wl[r * 128 + cc * 4]);
        acc[0].x = fmaf(xv.x, wv.x, acc[0].x); acc[0].y = fmaf(xv.y, wv.x, acc[0].y);
        acc[0].z = fmaf(xv.z, wv.x, acc[0].z); acc[0].w = fmaf(xv.w, wv.x, acc[0].w);
        acc[1].x = fmaf(xv.x, wv.y, acc[1].x); acc[1].y = fmaf(xv.y, wv.y, acc[1].y);
        acc[1].z = fmaf(xv.z, wv.y, acc[1].z); acc[1].w = fmaf(xv.w, wv.y, acc[1].w);
        acc[2].x = fmaf(xv.x, wv.z, acc[2].x); acc[2].y = fmaf(xv.y, wv.z, acc[2].y);
        acc[2].z = fmaf(xv.z, wv.z, acc[2].z); acc[2].w = fmaf(xv.w, wv.z, acc[2].w);
        acc[3].x = fmaf(xv.x, wv.w, acc[3].x); acc[3].y = fmaf(xv.y, wv.w, acc[3].y);
        acc[3].z = fmaf(xv.z, wv.w, acc[3].z); acc[3].w = fmaf(xv.w, wv.w, acc[3].w);
    }
    const size_t base = (size_t)(n * 1024 + sp) * (NT * 128);
#pragma unroll
    for (int j = 0; j < 4; j++) {
        const int cb = cc * 4 + j;
        out[base + (tt * 4 + 0) * 128 + cb] = acc[j].x;
        out[base + (tt * 4 + 1) * 128 + cb] = acc[j].y;
        out[base + (tt * 4 + 2) * 128 + cb] = acc[j].z;
        out[base + (tt * 4 + 3) * 128 + cb] = acc[j].w;
    }
}

// ---------------- exact 3-way bf16 split: w[CO][CIN*9] -> {hi,mid,lo}[9][CO][CIN] ----------------
__global__ void split_w(const float* __restrict__ w,
                        unsigned short* __restrict__ hi, unsigned short* __restrict__ mid,
                        unsigned short* __restrict__ lo, int CO, int CIN_)
{
    const int idx = blockIdx.x * blockDim.x + threadIdx.x;
    if (idx >= CO * CIN_) return;
    const int co = idx / CIN_, ci = idx % CIN_;
    const float* src = w + ((size_t)co * CIN_ + ci) * 9;
#pragma unroll
    for (int k = 0; k < 9; ++k) {
        const float f = src[k];
        const unsigned u = __float_as_uint(f);
        const float fh = __uint_as_float(u & 0xFFFF0000u);
        const float r1 = f - fh;
        const unsigned u1 = __float_as_uint(r1);
        const float fm = __uint_as_float(u1 & 0xFFFF0000u);
        const float r2 = r1 - fm;
        const unsigned u2 = __float_as_uint(r2);
        const size_t dst = ((size_t)k * CO + co) * CIN_ + ci;
        hi[dst] = (unsigned short)(u >> 16);
        mid[dst] = (unsigned short)(u1 >> 16);
        lo[dst] = (unsigned short)(u2 >> 16);
    }
}

// ---------------- MFMA conv: spikes (N,H,W,T,CIN) bf16 -> out (N,HO,WO,T,COUT) fp32 ----------------
template<int CIN_SEG, int COUT, int H, int W, int PAD, int BM, int BN, int NSPLIT>
__global__ __launch_bounds__(256, 2) void conv_mfma(
    const unsigned short* __restrict__ spk,
    const unsigned short* __restrict__ wlo, const unsigned short* __restrict__ wmid,
    const unsigned short* __restrict__ whi,
    const float* __restrict__ bias, float* __restrict__ out)
{
    constexpr int CIN = CIN_SEG * NSPLIT;
    constexpr int HO = PAD ? H : H - 2;
    constexpr int WO = PAD ? W : W - 2;
    constexpr int MROW = WO * NT;
    constexpr int MTILES = (MROW + BM - 1) / BM;
    constexpr int WAVES_N = BN / 32;
    constexpr int KC = CIN_SEG / 64;
    __shared__ unsigned short smem[BM * 64 + 3 * BN * 64];

    const int tid = threadIdx.x;
    const int lane = tid & 63;
    const int wv = tid >> 6;
    const int wm = wv / WAVES_N;
    const int wn = wv % WAVES_N;
    const int lr = lane >> 4;   // 0..3
    const int lc = lane & 15;

    const int bx = blockIdx.x;
    const int ho = bx / MTILES;
    const int m0 = (bx % MTILES) * BM;
    const int co0 = blockIdx.y * BN;
    const int n = blockIdx.z / NSPLIT;
    const int split = blockIdx.z % NSPLIT;

    f32x4 acc[4][2];
#pragma unroll
    for (int mf = 0; mf < 4; ++mf)
#pragma unroll
        for (int nf = 0; nf < 2; ++nf) {
            const float bv = (NSPLIT == 1 || split == 0)
                ? bias[co0 + wn * 32 + nf * 16 + lc] : 0.f;
            acc[mf][nf] = {bv, bv, bv, bv};
        }

    const unsigned short* wp[3] = {wlo, wmid, whi};

    for (int kh = 0; kh < 3; ++kh) {
        const int hirow = ho + kh - PAD;
        if (hirow < 0 || hirow >= H) continue;
        const size_t inrow = (size_t)(n * H + hirow) * (W * NT);
        for (int kw = 0; kw < 3; ++kw) {
            const int kwp = kw - PAD;
            const int khw = kh * 3 + kw;
            for (int kc = 0; kc < KC; ++kc) {
                const int ci0 = split * CIN_SEG + kc * 64;
                // ---- stage A (reg -> swizzled LDS), zero-fill masked rows ----
#pragma unroll
                for (int it = 0; it < BM / 32; ++it) {
                    const int idx = it * 256 + tid;
                    const int r = idx >> 3, b = idx & 7;
                    const int mg = m0 + r + kwp * NT;
                    s16x8 v = {0, 0, 0, 0, 0, 0, 0, 0};
                    if ((m0 + r) < MROW && mg >= 0 && mg < W * NT)
                        v = *(const s16x8*)(spk + (inrow + mg) * CIN + ci0 + b * 8);
                    *(s16x8*)&smem[r * 64 + ((b ^ (r & 7)) << 3)] = v;
                }
                // ---- stage B x3 splits ----
#pragma unroll
                for (int s = 0; s < 3; ++s) {
                    const unsigned short* wsrc = wp[s] + ((size_t)(khw * COUT + co0)) * CIN + ci0;
#pragma unroll
                    for (int it = 0; it < BN / 32; ++it) {
                        const int idx = it * 256 + tid;
                        const int r = idx >> 3, b = idx & 7;
                        const s16x8 v = *(const s16x8*)(wsrc + (size_t)r * CIN + b * 8);
                        *(s16x8*)&smem[BM * 64 + s * BN * 64 + r * 64 + ((b ^ (r & 7)) << 3)] = v;
                    }
                }
                __syncthreads();
#pragma unroll
                for (int kcs = 0; kcs < 2; ++kcs) {
                    const int c16 = kcs * 4 + lr;
                    s16x8 af[4];
#pragma unroll
                    for (int mf = 0; mf < 4; ++mf) {
                        const int ra = wm * 64 + mf * 16 + lc;
                        af[mf] = *(const s16x8*)&smem[ra * 64 + ((c16 ^ (ra & 7)) << 3)];
                    }
#pragma unroll
                    for (int s = 0; s < 3; ++s) {
#pragma unroll
                        for (int nf = 0; nf < 2; ++nf) {
                            const int rb = wn * 32 + nf * 16 + lc;
                            const s16x8 bf_ = *(const s16x8*)&smem[BM * 64 + s * BN * 64 + rb * 64 + ((c16 ^ (rb & 7)) << 3)];
#pragma unroll
                            for (int mf = 0; mf < 4; ++mf)
                                acc[mf][nf] = __builtin_amdgcn_mfma_f32_16x16x32_bf16(
                                    af[mf], bf_, acc[mf][nf], 0, 0, 0);
                        }
                    }
                }
                __syncthreads();
            }
        }
    }

    const size_t SLAB = (size_t)2 * HO * WO * NT * COUT;
    float* outp = out + (size_t)split * SLAB + (size_t)(n * HO + ho) * (WO * NT) * COUT;
#pragma unroll
    for (int mf = 0; mf < 4; ++mf) {
        const int mbase = m0 + wm * 64 + mf * 16;
        if (mbase >= MROW) continue;
#pragma unroll
        for (int nf = 0; nf < 2; ++nf) {
            const int col = co0 + wn * 32 + nf * 16 + lc;
#pragma unroll
            for (int j = 0; j < 4; ++j) {
                const int m = mbase + lr * 4 + j;
                outp[(size_t)m * COUT + col] = acc[mf][nf][j];
            }
        }
    }
}

// ---------------- IF scan, channel-innermost: fp32 conv-out -> bf16 spikes ----------------
__global__ void if_ci(const float* __restrict__ in, unsigned short* __restrict__ spk,
                      const float* __restrict__ thr, int C, int total)
{
    const int idx = blockIdx.x * blockDim.x + threadIdx.x;
    if (idx >= total) return;
    const int c = idx % C;
    const size_t base = (size_t)(idx / C) * NT * C + c;
    const float th = thr[c];
    float v = 0.f;
#pragma unroll
    for (int t = 0; t < NT; ++t) {
        const float x = in[base + (size_t)t * C];
        v += x;
        const float s = (v >= th) ? 1.f : 0.f;
        v -= s * th;
        spk[base + (size_t)t * C] = s != 0.f ? (unsigned short)0x3F80 : (unsigned short)0;
    }
}

// ---------------- pool 2x2 + IF, channel-innermost, bf16 spikes in/out ----------------
__global__ void pool_ci(const unsigned short* __restrict__ in, unsigned short* __restrict__ out,
                        const float* __restrict__ thr, int C, int HO, int WO, int total)
{
    const int idx = blockIdx.x * blockDim.x + threadIdx.x;
    if (idx >= total) return;
    const int c = idx % C;
    const int sp = idx / C;
    const int wo = sp % WO;
    const int ho = (sp / WO) % HO;
    const int n = sp / (WO * HO);
    const int H = 2 * HO, W = 2 * WO;
    const size_t b00 = (((size_t)(n * H + 2 * ho) * W + 2 * wo) * NT) * C + c;
    const size_t oB = (((size_t)(n * HO + ho) * WO + wo) * NT) * C + c;
    const size_t dW = (size_t)NT * C, dH = (size_t)W * NT * C;
    const float th = thr[c];
    float v = 0.f;
#pragma unroll
    for (int t = 0; t < NT; ++t) {
        const size_t o = (size_t)t * C;
        const float a = bf2f(in[b00 + o]) + bf2f(in[b00 + dW + o]) +
                        bf2f(in[b00 + dH + o]) + bf2f(in[b00 + dH + dW + o]);
        v += a * 0.25f;
        const float s = (v >= th) ? 1.f : 0.f;
        v -= s * th;
        out[oB + o] = s != 0.f ? (unsigned short)0x3F80 : (unsigned short)0;
    }
}

// ---------------- conv7 4-way partial reduce + IF -> bf16 spikes ----------------
__global__ void reduce_if7(const float* __restrict__ part, unsigned short* __restrict__ out,
                           const float* __restrict__ thr, int total)
{
    const int idx = blockIdx.x * blockDim.x + threadIdx.x;
    if (idx >= total) return;
    const int c = idx & 1023;
    const size_t base = (size_t)(idx >> 10) * NT * 1024 + c;
    const size_t SL = 327680;
    const float th = thr[c];
    float v = 0.f;
#pragma unroll
    for (int t = 0; t < NT; ++t) {
        const size_t o = (size_t)t * 1024;
        const float x = part[base + o] + part[SL + base + o] +
                        part[2 * SL + base + o] + part[3 * SL + base + o];
        v += x;
        const float s = (v >= th) ? 1.f : 0.f;
        v -= s * th;
        out[base + o] = s != 0.f ? (unsigned short)0x3F80 : (unsigned short)0;
    }
}

// ---------------- classifier: bf16 spikes (N,T,1024) ----------------
__global__ __launch_bounds__(1024) void classifier_ci(
    const unsigned short* __restrict__ s, const float* __restrict__ wc,
    const float* __restrict__ bc, float* __restrict__ out)
{
    __shared__ float cnt[2][1024];
    const int c = threadIdx.x;
    for (int n = 0; n < 2; n++) {
        float sum = 0.f;
#pragma unroll
        for (int t = 0; t < NT; ++t) sum += bf2f(s[(size_t)(n * NT + t) * 1024 + c]);
        cnt[n][c] = sum;
    }
    __syncthreads();
    if (threadIdx.x < 20) {
        const int n = threadIdx.x / 10, o = threadIdx.x % 10;
        float a = 0.f;
        for (int k = 0; k < 1024; k++) a += cnt[n][k] * wc[o * 1024 + k];
        out[n * 10 + o] = a * (1.f / 40.f) + bc[o];
    }
}

extern "C" void kernel_launch(void* const* d_in, const int* in_sizes, int n_in,
                              void* d_out, int out_size, void* d_ws, size_t ws_size,
                              hipStream_t stream)
{
    const float* x   = (const float*)d_in[0];
    const float* w1  = (const float*)d_in[1];  const float* b1 = (const float*)d_in[2];
    const float* w2  = (const float*)d_in[3];  const float* b2 = (const float*)d_in[4];
    const float* w3  = (const float*)d_in[5];  const float* b3 = (const float*)d_in[6];
    const float* w4  = (const float*)d_in[7];  const float* b4 = (const float*)d_in[8];
    const float* w5  = (const float*)d_in[9];  const float* b5 = (const float*)d_in[10];
    const float* w6  = (const float*)d_in[11]; const float* b6 = (const float*)d_in[12];
    const float* w7  = (const float*)d_in[13]; const float* b7 = (const float*)d_in[14];
    const float* wc  = (const float*)d_in[15]; const float* bc = (const float*)d_in[16];
    const float* thr1 = (const float*)d_in[17];
    const float* thr2 = (const float*)d_in[18];
    const float* p1   = (const float*)d_in[19];
    const float* thr3 = (const float*)d_in[20];
    const float* thr4 = (const float*)d_in[21];
    const float* p2   = (const float*)d_in[22];
    const float* thr5 = (const float*)d_in[23];
    const float* thr6 = (const float*)d_in[24];
    const float* p3   = (const float*)d_in[25];
    const float* thr7 = (const float*)d_in[26];
    const float* p4   = (const float*)d_in[27];

    char* W0 = (char*)d_ws;
    float* OUT = (float*)W0;                                   // 44 MB fp32 conv-out (+conv7 slabs)
    unsigned short* SPKA = (unsigned short*)(W0 + ((size_t)44 << 20));  // 22 MB
    unsigned short* SPKB = (unsigned short*)(W0 + ((size_t)66 << 20));  // 22 MB
    unsigned short* WH   = (unsigned short*)(W0 + ((size_t)88 << 20));  // 3 x 9.44 MB
    unsigned short* WMID = WH + 4718592;
    unsigned short* WLO  = WH + 2 * 4718592;
    float* WT1 = (float*)(W0 + ((size_t)118 << 20));           // 13.8 KB
    float* O = (float*)d_out;

    // conv1 (fp32) + IF
    transpose_w<<<dim3(1, 4), 256, 0, stream>>>(w1, WT1, 128, 27);
    conv1_c<<<dim3(1024, 1, 2), 320, 0, stream>>>(x, WT1, b1, OUT);
    if_ci<<<1024, 256, 0, stream>>>(OUT, SPKA, thr1, 128, 262144);

    // L2
    split_w<<<64, 256, 0, stream>>>(w2, WH, WMID, WLO, 128, 128);
    conv_mfma<128, 128, 32, 32, 1, 128, 64, 1><<<dim3(320, 2, 2), 256, 0, stream>>>(SPKA, WLO, WMID, WH, b2, OUT);
    if_ci<<<1024, 256, 0, stream>>>(OUT, SPKB, thr2, 128, 262144);
    pool_ci<<<256, 256, 0, stream>>>(SPKB, SPKA, p1, 128, 16, 16, 65536);

    // L3
    split_w<<<128, 256, 0, stream>>>(w3, WH, WMID, WLO, 256, 128);
    conv_mfma<128, 256, 16, 16, 1, 128, 64, 1><<<dim3(80, 4, 2), 256, 0, stream>>>(SPKA, WLO, WMID, WH, b3, OUT);
    if_ci<<<512, 256, 0, stream>>>(OUT, SPKB, thr3, 256, 131072);

    // L4
    split_w<<<256, 256, 0, stream>>>(w4, WH, WMID, WLO, 256, 256);
    conv_mfma<256, 256, 16, 16, 1, 128, 64, 1><<<dim3(80, 4, 2), 256, 0, stream>>>(SPKB, WLO, WMID, WH, b4, OUT);
    if_ci<<<512, 256, 0, stream>>>(OUT, SPKA, thr4, 256, 131072);
    pool_ci<<<128, 256, 0, stream>>>(SPKA, SPKB, p2, 256, 8, 8, 32768);

    // L5
    split_w<<<512, 256, 0, stream>>>(w5, WH, WMID, WLO, 512, 256);
    conv_mfma<256, 512, 8, 8, 1, 64, 128, 1><<<dim3(40, 4, 2), 256, 0, stream>>>(SPKB, WLO, WMID, WH, b5, OUT);
    if_ci<<<256, 256, 0, stream>>>(OUT, SPKA, thr5, 512, 65536);

    // L6
    split_w<<<1024, 256, 0, stream>>>(w6, WH, WMID, WLO, 512, 512);
    conv_mfma<512, 512, 8, 8, 1, 64, 128, 1><<<dim3(40, 4, 2), 256, 0, stream>>>(SPKA, WLO, WMID, WH, b6, OUT);
    if_ci<<<256, 256, 0, stream>>>(OUT, SPKB, thr6, 512, 65536);
    pool_ci<<<64, 256, 0, stream>>>(SPKB, SPKA, p3, 512, 4, 4, 16384);

    // L7: K-split x4 -> partial slabs in OUT, then reduce+IF
    split_w<<<2048, 256, 0, stream>>>(w7, WH, WMID, WLO, 1024, 512);
    conv_mfma<128, 1024, 4, 4, 0, 64, 128, 4><<<dim3(4, 8, 8), 256, 0, stream>>>(SPKA, WLO, WMID, WH, b7, OUT);
    reduce_if7<<<32, 256, 0, stream>>>(OUT, SPKB, thr7, 8192);
    pool_ci<<<8, 256, 0, stream>>>(SPKB, SPKA, p4, 1024, 1, 1, 2048);

    // classifier
    classifier_ci<<<1, 1024, 0, stream>>>(SPKA, wc, bc, O);
}